// Round 2
// baseline (321.530 us; speedup 1.0000x reference)
//
#include <hip/hip_runtime.h>

#define B_ 4
#define L_ 2048
#define DM 512
#define DI 1024
#define DS 16
#define DR 32
#define M_ (B_ * L_)

typedef unsigned short ushort_t;
typedef __attribute__((ext_vector_type(8))) short short8;
typedef __attribute__((ext_vector_type(4))) float floatx4;
typedef __attribute__((ext_vector_type(4))) unsigned int uint4v;

__device__ __forceinline__ float bf2f(ushort_t u) {
    union { unsigned int i; float f; } v; v.i = ((unsigned int)u) << 16; return v.f;
}
__device__ __forceinline__ ushort_t f2bf(float f) {
    union { float f; unsigned int i; } v; v.f = f;
    unsigned int x = v.i;
    x += 0x7fffu + ((x >> 16) & 1u);
    return (ushort_t)(x >> 16);
}
__device__ __forceinline__ float silu_f(float x) { return x / (1.f + __expf(-x)); }
__device__ __forceinline__ float softplus_f(float x) {
    return x > 20.f ? x : __logf(1.f + __expf(x));
}

// ---------------------------------------------------------------------------
// Dtype detection: read x_seq as bf16 at EVEN indices. If the buffer actually
// holds fp32, even bf16 slots are float mantissa halves -> random exponents,
// mostly outside [2^-42, 2^43]. If it holds bf16 N(0,1) data, exponents
// cluster near 127. flag = 1 => fp32 storage.
// ---------------------------------------------------------------------------
__global__ void detect_dtype_kernel(const ushort_t* __restrict__ p, int* __restrict__ flag) {
    if (threadIdx.x == 0 && blockIdx.x == 0) {
        int outl = 0;
        for (int i = 0; i < 256; ++i) {
            ushort_t u = p[2 * i];
            int e = (u >> 7) & 0xFF;
            if (e < 85 || e > 170) outl++;
        }
        *flag = (outl > 64) ? 1 : 0;
    }
}

// Canonicalize an input tensor to bf16 scratch (reads fp32 or bf16 per flag).
__global__ __launch_bounds__(256) void convert_in_kernel(
    const void* __restrict__ src, ushort_t* __restrict__ dst, int n,
    const int* __restrict__ flag) {
    int i = blockIdx.x * 256 + threadIdx.x;
    if (i >= n) return;
    if (*flag)
        dst[i] = f2bf(((const float*)src)[i]);
    else
        dst[i] = ((const ushort_t*)src)[i];
}

// ---------------------------------------------------------------------------
// Generic bf16 GEMM:  C[M,N] = A[M,K] * Bw[N,K]^T   (both K-major)
// 64x64 tile, BK=32, 256 threads (4 waves), MFMA 16x16x32 bf16.
// EPI: 0 = store bf16, 2 = softplus(acc + bias[n]) then store bf16
// ---------------------------------------------------------------------------
#define TILE 64
#define BK 32
#define LSTR 40   // 32 + 8 pad

template <int EPI>
__global__ __launch_bounds__(256) void gemm_bt(
    const ushort_t* __restrict__ A, const ushort_t* __restrict__ Bw,
    ushort_t* __restrict__ C, const ushort_t* __restrict__ bias,
    int M, int N, int K, int lda, int ldb)
{
    __shared__ __align__(16) ushort_t As[TILE * LSTR];
    __shared__ __align__(16) ushort_t Bs[TILE * LSTR];

    const int tid = threadIdx.x;
    const int m0 = blockIdx.x * TILE;
    const int n0 = blockIdx.y * TILE;
    const int wave = tid >> 6, lane = tid & 63;
    const int quad = lane >> 4, lrow = lane & 15;

    const int srow = tid >> 2;         // 0..63
    const int scol = (tid & 3) * 8;    // 0,8,16,24

    floatx4 acc[4] = {floatx4{0,0,0,0}, floatx4{0,0,0,0},
                      floatx4{0,0,0,0}, floatx4{0,0,0,0}};

    for (int k0 = 0; k0 < K; k0 += BK) {
        uint4v av = *(const uint4v*)&A[(size_t)(m0 + srow) * lda + k0 + scol];
        uint4v bv = *(const uint4v*)&Bw[(size_t)(n0 + srow) * ldb + k0 + scol];
        __syncthreads();
        *(uint4v*)&As[srow * LSTR + scol] = av;
        *(uint4v*)&Bs[srow * LSTR + scol] = bv;
        __syncthreads();
        short8 af = *(const short8*)&As[(wave * 16 + lrow) * LSTR + quad * 8];
#pragma unroll
        for (int nt = 0; nt < 4; nt++) {
            short8 bf = *(const short8*)&Bs[(nt * 16 + lrow) * LSTR + quad * 8];
            acc[nt] = __builtin_amdgcn_mfma_f32_16x16x32_bf16(af, bf, acc[nt], 0, 0, 0);
        }
    }

#pragma unroll
    for (int nt = 0; nt < 4; nt++) {
#pragma unroll
        for (int r = 0; r < 4; r++) {
            int row = wave * 16 + quad * 4 + r;   // M index within tile
            int col = nt * 16 + lrow;             // N index within tile
            float v = acc[nt][r];
            if (EPI == 2) {
                v += bf2f(bias[n0 + col]);
                v = softplus_f(v);
            }
            C[(size_t)(m0 + row) * N + (n0 + col)] = f2bf(v);
        }
    }
}

// ---------------------------------------------------------------------------
// Causal depthwise conv (width 4) + bias + SiLU.  One thread per (m, d).
// ---------------------------------------------------------------------------
__global__ __launch_bounds__(256) void conv_silu_kernel(
    const ushort_t* __restrict__ x, const ushort_t* __restrict__ w,
    const ushort_t* __restrict__ b, ushort_t* __restrict__ xc)
{
    int idx = blockIdx.x * 256 + threadIdx.x;       // over M_*DI
    int d = idx & (DI - 1);
    int m = idx >> 10;
    int l = m & (L_ - 1);
    float acc = bf2f(b[d]);
#pragma unroll
    for (int k = 0; k < 4; k++) {
        int l2 = l - 3 + k;
        if (l2 >= 0)
            acc += bf2f(x[(size_t)(m - 3 + k) * DI + d]) * bf2f(w[d * 4 + k]);
    }
    xc[idx] = f2bf(silu_f(acc));
}

// ---------------------------------------------------------------------------
// Selective scan. Grid: 256 blocks = b(4) x s(16) x dq(4); 256 threads = d.
// ---------------------------------------------------------------------------
__global__ __launch_bounds__(256) void scan_kernel(
    const ushort_t* __restrict__ delta_bf, const ushort_t* __restrict__ xc_bf,
    const ushort_t* __restrict__ xdbl, const ushort_t* __restrict__ A_log,
    float* __restrict__ y_scan)
{
    const int b = blockIdx.x >> 6;
    const int s = (blockIdx.x >> 2) & 15;
    const int dq = blockIdx.x & 3;
    const int d = dq * 256 + threadIdx.x;

    const float Aval = -__expf(bf2f(A_log[d * DS + s]));
    float h = 0.f;

    const size_t row0 = (size_t)b * L_;
#pragma unroll 8
    for (int t = 0; t < L_; ++t) {
        size_t base = (row0 + t) * DI + d;
        float delta = bf2f(delta_bf[base]);
        float u     = bf2f(xc_bf[base]);
        float Bv    = bf2f(xdbl[(row0 + t) * 64 + 32 + s]);
        float dA = __expf(delta * Aval);
        h = __builtin_fmaf(dA, h, delta * u * Bv);
    }
    float Cv = bf2f(xdbl[(row0 + L_ - 1) * 64 + 48 + s]);
    atomicAdd(&y_scan[b * DI + d], h * Cv);
}

// ---------------------------------------------------------------------------
__global__ __launch_bounds__(64) void zlast_kernel(
    const ushort_t* __restrict__ x_seq, const ushort_t* __restrict__ in_proj_w,
    float* __restrict__ z_last)
{
    int o = blockIdx.x;                 // 0 .. B_*DI-1
    int b = o >> 10, d = o & (DI - 1);
    int lane = threadIdx.x;
    const ushort_t* xr = &x_seq[(size_t)(b * L_ + L_ - 1) * DM];
    const ushort_t* wr = &in_proj_w[(size_t)(DI + d) * DM];
    float v = 0.f;
#pragma unroll
    for (int k = 0; k < DM / 64; k++)
        v += bf2f(xr[lane + k * 64]) * bf2f(wr[lane + k * 64]);
#pragma unroll
    for (int off = 32; off > 0; off >>= 1) v += __shfl_down(v, off);
    if (lane == 0) z_last[o] = v;
}

// ---------------------------------------------------------------------------
__global__ __launch_bounds__(256) void gate_kernel(
    const float* __restrict__ y_scan, const ushort_t* __restrict__ xc_bf,
    const ushort_t* __restrict__ Dv, const float* __restrict__ z_last,
    float* __restrict__ y_last)
{
    int idx = blockIdx.x * 256 + threadIdx.x;   // 0 .. B_*DI-1
    int b = idx >> 10, d = idx & (DI - 1);
    float u_last = bf2f(xc_bf[(size_t)(b * L_ + L_ - 1) * DI + d]);
    float y = y_scan[idx] + u_last * bf2f(Dv[d]);
    y_last[idx] = y * silu_f(z_last[idx]);
}

// ---------------------------------------------------------------------------
// out[b,e] = y_last[b,:] . out_proj_w[e,:]; store dtype chosen by flag.
// ---------------------------------------------------------------------------
__global__ __launch_bounds__(64) void outproj_kernel(
    const float* __restrict__ y_last, const ushort_t* __restrict__ out_proj_w,
    void* __restrict__ out, const int* __restrict__ flag)
{
    int o = blockIdx.x;                 // 0 .. B_*DM-1
    int b = o >> 9;
    int lane = threadIdx.x;
    const float* yr = &y_last[b * DI];
    const ushort_t* wr = &out_proj_w[(size_t)(o & (DM - 1)) * DI];
    float v = 0.f;
#pragma unroll
    for (int k = 0; k < DI / 64; k++)
        v += yr[lane + k * 64] * bf2f(wr[lane + k * 64]);
#pragma unroll
    for (int off = 32; off > 0; off >>= 1) v += __shfl_down(v, off);
    if (lane == 0) {
        if (*flag) ((float*)out)[o] = v;
        else       ((ushort_t*)out)[o] = f2bf(v);
    }
}

// ---------------------------------------------------------------------------
extern "C" void kernel_launch(void* const* d_in, const int* in_sizes, int n_in,
                              void* d_out, int out_size, void* d_ws, size_t ws_size,
                              hipStream_t stream)
{
    char* ws = (char*)d_ws;
    // -------- ws layout (all offsets multiple of 256 bytes) --------
    int*      flag      = (int*)(ws + 0);
    ushort_t* c_xseq    = (ushort_t*)(ws + 1024);            //  8,388,608 B
    ushort_t* c_inproj  = (ushort_t*)(ws + 8389632);         //  2,097,152 B
    ushort_t* c_convw   = (ushort_t*)(ws + 10486784);        //      8,192 B
    ushort_t* c_convb   = (ushort_t*)(ws + 10494976);        //      2,048 B
    ushort_t* c_xprojw  = (ushort_t*)(ws + 10497024);        //    131,072 B
    ushort_t* c_dtprojw = (ushort_t*)(ws + 10628096);        //     65,536 B
    ushort_t* c_dtprojb = (ushort_t*)(ws + 10693632);        //      2,048 B
    ushort_t* c_alog    = (ushort_t*)(ws + 10695680);        //     32,768 B
    ushort_t* c_dv      = (ushort_t*)(ws + 10728448);        //      2,048 B
    ushort_t* c_outproj = (ushort_t*)(ws + 10730496);        //  1,048,576 B
    ushort_t* xc_bf     = (ushort_t*)(ws + 11779072);        // 16,777,216 B
    ushort_t* x_dbl     = (ushort_t*)(ws + 28556288);        //  1,048,576 B
    ushort_t* x_bf      = (ushort_t*)(ws + 29604864);        // 16,777,216 B (delta overlays after conv)
    ushort_t* delta_bf  = x_bf;                              // overlay: x dead after conv
    float*    z_last    = (float*)(ws + 46382080);
    float*    y_scan    = (float*)(ws + 46398464);
    float*    y_last    = (float*)(ws + 46414848);           // total ~44.3 MB

    // 0) detect storage dtype from x_seq bit patterns
    detect_dtype_kernel<<<1, 64, 0, stream>>>((const ushort_t*)d_in[0], flag);

    // canonicalize all inputs to bf16 scratch
    const int csz[10] = {B_*L_*DM, 2*DI*DM, DI*4, DI, 64*DI, DI*DR, DI, DI*DS, DI, DM*DI};
    ushort_t* cdst[10] = {c_xseq, c_inproj, c_convw, c_convb, c_xprojw,
                          c_dtprojw, c_dtprojb, c_alog, c_dv, c_outproj};
    for (int i = 0; i < 10; ++i)
        convert_in_kernel<<<(csz[i] + 255) / 256, 256, 0, stream>>>(
            d_in[i], cdst[i], csz[i], flag);

    // 1) in_proj (x half): x_bf = x_seq @ in_proj_w[0:DI]^T
    gemm_bt<0><<<dim3(M_ / TILE, DI / TILE), 256, 0, stream>>>(
        c_xseq, c_inproj, x_bf, nullptr, M_, DI, DM, DM, DM);

    // z at last token
    zlast_kernel<<<B_ * DI, 64, 0, stream>>>(c_xseq, c_inproj, z_last);

    // 2) causal conv + SiLU
    conv_silu_kernel<<<(M_ * DI) / 256, 256, 0, stream>>>(x_bf, c_convw, c_convb, xc_bf);

    // 3) x_proj: x_dbl = xc @ x_proj_w^T  (N=64)
    gemm_bt<0><<<dim3(M_ / TILE, 1), 256, 0, stream>>>(
        xc_bf, c_xprojw, x_dbl, nullptr, M_, 64, DI, DI, DI);

    // 4) dt_proj + softplus (delta overlays x_bf, which is dead after conv)
    gemm_bt<2><<<dim3(M_ / TILE, DI / TILE), 256, 0, stream>>>(
        x_dbl, c_dtprojw, delta_bf, c_dtprojb, M_, DI, DR, 64, DR);

    // 5) selective scan (y only at t = L-1)
    hipMemsetAsync(y_scan, 0, B_ * DI * sizeof(float), stream);
    scan_kernel<<<256, 256, 0, stream>>>(delta_bf, xc_bf, x_dbl, c_alog, y_scan);

    // 6) gate + 7) out projection (last token only)
    gate_kernel<<<(B_ * DI) / 256, 256, 0, stream>>>(y_scan, xc_bf, c_dv, z_last, y_last);
    outproj_kernel<<<B_ * DM, 64, 0, stream>>>(y_last, c_outproj, d_out, flag);
}

// Round 4
// 212.012 us; speedup vs baseline: 1.5166x; 1.5166x over previous
//
#include <hip/hip_runtime.h>

#define B_ 4
#define L_ 2048
#define DM 512
#define DI 1024
#define DS 16
#define DR 32
#define M_ (B_ * L_)

#define CHUNK 16
#define CL (L_ / CHUNK)   // 128 timesteps per chunk

typedef unsigned short ushort_t;
typedef __attribute__((ext_vector_type(8))) short short8;
typedef __attribute__((ext_vector_type(4))) float floatx4;
typedef __attribute__((ext_vector_type(4))) unsigned int uint4v;

__device__ __forceinline__ float bf2f(ushort_t u) {
    union { unsigned int i; float f; } v; v.i = ((unsigned int)u) << 16; return v.f;
}
__device__ __forceinline__ ushort_t f2bf(float f) {
    union { float f; unsigned int i; } v; v.f = f;
    unsigned int x = v.i;
    x += 0x7fffu + ((x >> 16) & 1u);
    return (ushort_t)(x >> 16);
}
__device__ __forceinline__ float silu_f(float x) { return x / (1.f + __expf(-x)); }
__device__ __forceinline__ float softplus_f(float x) {
    return x > 20.f ? x : __logf(1.f + __expf(x));
}

// ---------------------------------------------------------------------------
// Fused fp32 -> bf16 conversion of the 4 MFMA operands, 4 elements/thread.
// ---------------------------------------------------------------------------
#define N0 (B_ * L_ * DM)   // x_seq            4,194,304
#define N1 (DI * DM)        // in_proj (x half)   524,288
#define N2 (64 * DI)        // x_proj_w            65,536
#define N3 (DI * DR)        // dt_proj_w           32,768
#define NCONV ((N0 + N1 + N2 + N3) / 4)

__global__ __launch_bounds__(256) void convert4_kernel(
    const float* __restrict__ s0, ushort_t* __restrict__ d0,
    const float* __restrict__ s1, ushort_t* __restrict__ d1,
    const float* __restrict__ s2, ushort_t* __restrict__ d2,
    const float* __restrict__ s3, ushort_t* __restrict__ d3)
{
    int i = (blockIdx.x * 256 + threadIdx.x) * 4;
    const float* s; ushort_t* d;
    if (i < N0)                { s = s0; d = d0; }
    else if ((i -= N0) < N1)   { s = s1; d = d1; }
    else if ((i -= N1) < N2)   { s = s2; d = d2; }
    else if ((i -= N2) < N3)   { s = s3; d = d3; }
    else return;
    floatx4 v = *(const floatx4*)&s[i];
    ushort_t o[4] = {f2bf(v.x), f2bf(v.y), f2bf(v.z), f2bf(v.w)};
    *(uint2*)&d[i] = *(const uint2*)o;
}

// ---------------------------------------------------------------------------
// Generic bf16 GEMM:  C[M,N] = A[M,K] * Bw[N,K]^T  (both K-major)
// 64x64 tile, BK=32, 256 threads, MFMA 16x16x32 bf16.
// EPI: 0 = store bf16;  2 = softplus(acc + bias[n]) then store bf16
// ---------------------------------------------------------------------------
#define TILE 64
#define BK 32
#define LSTR 40

template <int EPI>
__global__ __launch_bounds__(256) void gemm_bt(
    const ushort_t* __restrict__ A, const ushort_t* __restrict__ Bw,
    ushort_t* __restrict__ C, const float* __restrict__ bias,
    int M, int N, int K, int lda, int ldb)
{
    __shared__ __align__(16) ushort_t As[TILE * LSTR];
    __shared__ __align__(16) ushort_t Bs[TILE * LSTR];

    const int tid = threadIdx.x;
    const int m0 = blockIdx.x * TILE;
    const int n0 = blockIdx.y * TILE;
    const int wave = tid >> 6, lane = tid & 63;
    const int quad = lane >> 4, lrow = lane & 15;
    const int srow = tid >> 2;
    const int scol = (tid & 3) * 8;

    floatx4 acc[4] = {floatx4{0,0,0,0}, floatx4{0,0,0,0},
                      floatx4{0,0,0,0}, floatx4{0,0,0,0}};

    for (int k0 = 0; k0 < K; k0 += BK) {
        uint4v av = *(const uint4v*)&A[(size_t)(m0 + srow) * lda + k0 + scol];
        uint4v bv = *(const uint4v*)&Bw[(size_t)(n0 + srow) * ldb + k0 + scol];
        __syncthreads();
        *(uint4v*)&As[srow * LSTR + scol] = av;
        *(uint4v*)&Bs[srow * LSTR + scol] = bv;
        __syncthreads();
        short8 af = *(const short8*)&As[(wave * 16 + lrow) * LSTR + quad * 8];
#pragma unroll
        for (int nt = 0; nt < 4; nt++) {
            short8 bf = *(const short8*)&Bs[(nt * 16 + lrow) * LSTR + quad * 8];
            acc[nt] = __builtin_amdgcn_mfma_f32_16x16x32_bf16(af, bf, acc[nt], 0, 0, 0);
        }
    }

#pragma unroll
    for (int nt = 0; nt < 4; nt++) {
#pragma unroll
        for (int r = 0; r < 4; r++) {
            int row = wave * 16 + quad * 4 + r;
            int col = nt * 16 + lrow;
            float v = acc[nt][r];
            if (EPI == 2) {
                v += bias[n0 + col];
                v = softplus_f(v);
            }
            C[(size_t)(m0 + row) * N + (n0 + col)] = f2bf(v);
        }
    }
}

// ---------------------------------------------------------------------------
// Causal depthwise conv (width 4) + bias + SiLU.  One thread per (m, d).
// ---------------------------------------------------------------------------
__global__ __launch_bounds__(256) void conv_silu_kernel(
    const ushort_t* __restrict__ x, const float* __restrict__ w,
    const float* __restrict__ b, ushort_t* __restrict__ xc)
{
    int idx = blockIdx.x * 256 + threadIdx.x;
    int d = idx & (DI - 1);
    int m = idx >> 10;
    int l = m & (L_ - 1);
    float acc = b[d];
#pragma unroll
    for (int k = 0; k < 4; k++) {
        int l2 = l - 3 + k;
        if (l2 >= 0)
            acc += bf2f(x[(size_t)(m - 3 + k) * DI + d]) * w[d * 4 + k];
    }
    xc[idx] = f2bf(silu_f(acc));
}

// ---------------------------------------------------------------------------
// Chunked selective scan, pass 1: per (chunk, b, s, d) compute
//   P = prod dA,  S = chunk-local state (h starting from 0).
// Grid 1024 blocks: bx = sq(4) | b(4) | dq(4) | c(16).  4 s per thread.
// ---------------------------------------------------------------------------
__global__ __launch_bounds__(256) void scan_chunk_kernel(
    const ushort_t* __restrict__ delta_bf, const ushort_t* __restrict__ xc_bf,
    const ushort_t* __restrict__ xdbl, const float* __restrict__ A_log,
    float* __restrict__ Pc, float* __restrict__ Sc)
{
    const int bx = blockIdx.x;
    const int c  = bx & 15;
    const int dq = (bx >> 4) & 3;
    const int b  = (bx >> 6) & 3;
    const int sq = bx >> 8;
    const int tid = threadIdx.x;
    const int d = dq * 256 + tid;

    __shared__ float Bsh[CL][4];
    if (tid < CL) {
        size_t row = (size_t)b * L_ + c * CL + tid;
        uint2 v = *(const uint2*)&xdbl[row * 64 + 32 + sq * 4];
        Bsh[tid][0] = bf2f((ushort_t)(v.x & 0xffff));
        Bsh[tid][1] = bf2f((ushort_t)(v.x >> 16));
        Bsh[tid][2] = bf2f((ushort_t)(v.y & 0xffff));
        Bsh[tid][3] = bf2f((ushort_t)(v.y >> 16));
    }
    float Av[4];
#pragma unroll
    for (int j = 0; j < 4; j++)
        Av[j] = -__expf(A_log[d * DS + sq * 4 + j]);
    __syncthreads();

    float P[4] = {1.f, 1.f, 1.f, 1.f};
    float S[4] = {0.f, 0.f, 0.f, 0.f};
    size_t base = ((size_t)b * L_ + c * CL) * DI + d;
#pragma unroll 4
    for (int t = 0; t < CL; ++t) {
        float delta = bf2f(delta_bf[base]);
        float du = delta * bf2f(xc_bf[base]);
        base += DI;
#pragma unroll
        for (int j = 0; j < 4; j++) {
            float dA = __expf(delta * Av[j]);
            S[j] = __builtin_fmaf(dA, S[j], du * Bsh[t][j]);
            P[j] *= dA;
        }
    }
#pragma unroll
    for (int j = 0; j < 4; j++) {
        size_t o = (((size_t)c * 4 + b) * 16 + (sq * 4 + j)) * 1024 + d;
        Pc[o] = P[j];
        Sc[o] = S[j];
    }
}

// ---------------------------------------------------------------------------
// Scan pass 2: fold 16 chunks per (b,s,d), multiply by C_last, reduce over s.
// ---------------------------------------------------------------------------
__global__ __launch_bounds__(256) void scan_combine_kernel(
    const float* __restrict__ Pc, const float* __restrict__ Sc,
    const ushort_t* __restrict__ xdbl, float* __restrict__ y_scan)
{
    int gid = blockIdx.x * 256 + threadIdx.x;   // 65536 = b*s*d
    int d = gid & 1023;
    int s = (gid >> 10) & 15;
    int b = gid >> 14;
    float h = 0.f;
#pragma unroll
    for (int c = 0; c < CHUNK; ++c) {
        size_t o = (((size_t)c * 4 + b) * 16 + s) * 1024 + d;
        h = __builtin_fmaf(Pc[o], h, Sc[o]);
    }
    float Cv = bf2f(xdbl[((size_t)b * L_ + L_ - 1) * 64 + 48 + s]);
    atomicAdd(&y_scan[b * DI + d], h * Cv);
}

// ---------------------------------------------------------------------------
// z at last token (fp32 inputs): z_last[b,d] = x_seq[b,L-1,:] . in_proj_w[DI+d,:]
// ---------------------------------------------------------------------------
__global__ __launch_bounds__(64) void zlast_kernel(
    const float* __restrict__ x_seq, const float* __restrict__ in_proj_w,
    float* __restrict__ z_last)
{
    int o = blockIdx.x;                 // 0 .. B_*DI-1
    int b = o >> 10, d = o & (DI - 1);
    int lane = threadIdx.x;
    const float* xr = &x_seq[(size_t)(b * L_ + L_ - 1) * DM];
    const float* wr = &in_proj_w[(size_t)(DI + d) * DM];
    float v = 0.f;
#pragma unroll
    for (int k = 0; k < DM / 64; k++)
        v += xr[lane + k * 64] * wr[lane + k * 64];
#pragma unroll
    for (int off = 32; off > 0; off >>= 1) v += __shfl_down(v, off);
    if (lane == 0) z_last[o] = v;
}

// ---------------------------------------------------------------------------
__global__ __launch_bounds__(256) void gate_kernel(
    const float* __restrict__ y_scan, const ushort_t* __restrict__ xc_bf,
    const float* __restrict__ Dv, const float* __restrict__ z_last,
    float* __restrict__ y_last)
{
    int idx = blockIdx.x * 256 + threadIdx.x;   // 0 .. B_*DI-1
    int b = idx >> 10, d = idx & (DI - 1);
    float u_last = bf2f(xc_bf[(size_t)(b * L_ + L_ - 1) * DI + d]);
    float y = y_scan[idx] + u_last * Dv[d];
    y_last[idx] = y * silu_f(z_last[idx]);
}

// ---------------------------------------------------------------------------
// out[b,e] = y_last[b,:] . out_proj_w[e,:]  (fp32 weights, fp32 out)
// ---------------------------------------------------------------------------
__global__ __launch_bounds__(64) void outproj_kernel(
    const float* __restrict__ y_last, const float* __restrict__ out_proj_w,
    float* __restrict__ out)
{
    int o = blockIdx.x;                 // 0 .. B_*DM-1
    int b = o >> 9;
    int lane = threadIdx.x;
    const float* yr = &y_last[b * DI];
    const float* wr = &out_proj_w[(size_t)(o & (DM - 1)) * DI];
    float v = 0.f;
#pragma unroll
    for (int k = 0; k < DI / 64; k++)
        v += yr[lane + k * 64] * wr[lane + k * 64];
#pragma unroll
    for (int off = 32; off > 0; off >>= 1) v += __shfl_down(v, off);
    if (lane == 0) out[o] = v;
}

// ---------------------------------------------------------------------------
extern "C" void kernel_launch(void* const* d_in, const int* in_sizes, int n_in,
                              void* d_out, int out_size, void* d_ws, size_t ws_size,
                              hipStream_t stream)
{
    const float* x_seq     = (const float*)d_in[0];
    const float* in_proj_w = (const float*)d_in[1];
    const float* conv_w    = (const float*)d_in[2];
    const float* conv_b    = (const float*)d_in[3];
    const float* x_proj_w  = (const float*)d_in[4];
    const float* dt_proj_w = (const float*)d_in[5];
    const float* dt_proj_b = (const float*)d_in[6];
    const float* A_log     = (const float*)d_in[7];
    const float* Dv        = (const float*)d_in[8];
    const float* out_proj_w= (const float*)d_in[9];
    float* out_f           = (float*)d_out;

    char* ws = (char*)d_ws;
    // ws layout (bytes). c_xseq dies after gemm1; Pc/Sc overlay it.
    ushort_t* c_xseq    = (ushort_t*)(ws + 0);          //  8,388,608
    float*    Pc        = (float*)(ws + 0);             //  4,194,304 (overlay)
    float*    Sc        = (float*)(ws + 4194304);       //  4,194,304 (overlay)
    ushort_t* c_inproj  = (ushort_t*)(ws + 8388608);    //  1,048,576
    ushort_t* c_xprojw  = (ushort_t*)(ws + 9437184);    //    131,072
    ushort_t* c_dtprojw = (ushort_t*)(ws + 9568256);    //     65,536
    ushort_t* x_bf      = (ushort_t*)(ws + 9633792);    // 16,777,216 (delta overlays)
    ushort_t* delta_bf  = x_bf;                         // x dead after conv
    ushort_t* xc_bf     = (ushort_t*)(ws + 26411008);   // 16,777,216
    ushort_t* x_dbl     = (ushort_t*)(ws + 43188224);   //  1,048,576
    float*    y_scan    = (float*)(ws + 44236800);      //     16,384
    float*    z_last    = (float*)(ws + 44253184);      //     16,384
    float*    y_last    = (float*)(ws + 44269568);      //     16,384

    // 0) convert MFMA operands to bf16 (one fused kernel)
    convert4_kernel<<<(NCONV + 255) / 256, 256, 0, stream>>>(
        x_seq, c_xseq, in_proj_w, c_inproj, x_proj_w, c_xprojw, dt_proj_w, c_dtprojw);

    // 1) in_proj (x half): x_bf = x_seq @ in_proj_w[0:DI]^T
    gemm_bt<0><<<dim3(M_ / TILE, DI / TILE), 256, 0, stream>>>(
        c_xseq, c_inproj, x_bf, nullptr, M_, DI, DM, DM, DM);

    // z at last token (fp32 path, independent)
    zlast_kernel<<<B_ * DI, 64, 0, stream>>>(x_seq, in_proj_w, z_last);

    // 2) causal conv + SiLU
    conv_silu_kernel<<<(M_ * DI) / 256, 256, 0, stream>>>(x_bf, conv_w, conv_b, xc_bf);

    // 3) x_proj: x_dbl = xc @ x_proj_w^T  (N=64)
    gemm_bt<0><<<dim3(M_ / TILE, 1), 256, 0, stream>>>(
        xc_bf, c_xprojw, x_dbl, nullptr, M_, 64, DI, DI, DI);

    // 4) dt_proj + softplus (delta overlays x_bf)
    gemm_bt<2><<<dim3(M_ / TILE, DI / TILE), 256, 0, stream>>>(
        x_dbl, c_dtprojw, delta_bf, dt_proj_b, M_, DI, DR, 64, DR);

    // 5) chunked selective scan
    scan_chunk_kernel<<<1024, 256, 0, stream>>>(delta_bf, xc_bf, x_dbl, A_log, Pc, Sc);
    (void)hipMemsetAsync(y_scan, 0, B_ * DI * sizeof(float), stream);
    scan_combine_kernel<<<256, 256, 0, stream>>>(Pc, Sc, x_dbl, y_scan);

    // 6) gate + 7) out projection (last token only)
    gate_kernel<<<(B_ * DI) / 256, 256, 0, stream>>>(y_scan, xc_bf, Dv, z_last, y_last);
    outproj_kernel<<<B_ * DM, 64, 0, stream>>>(y_last, out_proj_w, out_f);
}